// Round 8
// baseline (150.245 us; speedup 1.0000x reference)
//
#include <hip/hip_runtime.h>
#include <math.h>

#define NOISE 1e-12f
#define WSZ 1064   // per-wave LDS floats: theta(200) | G1(400) | G2(400) | F(64)

__device__ __forceinline__ float2 cmul(float2 a, float2 b) {
    return make_float2(a.x*b.x - a.y*b.y, a.x*b.y + a.y*b.x);
}
// conj(a)*b
__device__ __forceinline__ float2 cconjmul(float2 a, float2 b) {
    return make_float2(a.x*b.x + a.y*b.y, a.x*b.y - a.y*b.x);
}
// a*conj(b)
__device__ __forceinline__ float2 cmulconj(float2 a, float2 b) {
    return make_float2(a.x*b.x + a.y*b.y, a.y*b.x - a.x*b.y);
}
__device__ __forceinline__ float2 cadd(float2 a, float2 b){ return make_float2(a.x+b.x, a.y+b.y); }
__device__ __forceinline__ float2 csub(float2 a, float2 b){ return make_float2(a.x-b.x, a.y-b.y); }
__device__ __forceinline__ float2 cscale(float s, float2 a){ return make_float2(s*a.x, s*a.y); }

// one wave per batch element iteration; 4 waves/block; 4 iterations -> 16 b per block
__global__ __launch_bounds__(256) void rate_kernel(
    const float* __restrict__ t1,
    const float* __restrict__ G1r, const float* __restrict__ G1i,
    const float* __restrict__ G2r, const float* __restrict__ G2i,
    const float* __restrict__ Ur,  const float* __restrict__ Ui,
    float* __restrict__ partial)
{
    __shared__ float lds[4 * WSZ];     // per-wave staging buffers
    __shared__ float2 ent[4][4][16];   // [wave][it][entry]
    __shared__ float wsum[4];
    const int wave = threadIdx.x >> 6;
    const int lane = threadIdx.x & 63;
    const int t  = lane & 7;     // output column of phi
    const int k0 = lane >> 3;    // k-strip (k = 8j + k0), reused as entry-octet id
    const int e8 = k0;
    const int nn = (e8 >> 1) & 1;   // = lane bit 4
    const int rr = e8 & 1;
    float* W = lds + wave * WSZ;

    // ---- register-held staging (issue-early / LDS-write-late, T14) ----
    float4 sv_tr, sv_ti, sv_ar, sv_ai, sv_br, sv_bi, sv_f;
    #define STAGE_LOAD(bb) {                                           \
        const float* tb_  = t1  + (long)(bb) * 264;                    \
        const float* g1r_ = G1r + (long)(bb) * 200;                    \
        const float* g1i_ = G1i + (long)(bb) * 200;                    \
        const float* g2r_ = G2r + (long)(bb) * 200;                    \
        const float* g2i_ = G2i + (long)(bb) * 200;                    \
        if (lane < 25) { sv_tr = ((const float4*)tb_)[lane];           \
                         sv_ti = ((const float4*)(tb_ + 100))[lane]; } \
        if (lane < 50) { sv_ar = ((const float4*)g1r_)[lane];          \
                         sv_ai = ((const float4*)g1i_)[lane];          \
                         sv_br = ((const float4*)g2r_)[lane];          \
                         sv_bi = ((const float4*)g2i_)[lane]; }        \
        if (lane < 16)   sv_f  = ((const float4*)(tb_ + 200))[lane];   \
    }
    #define STAGE_WRITE() {                                            \
        if (lane < 25) {                                               \
            float2* d = (float2*)W + lane * 4;                         \
            d[0] = make_float2(sv_tr.x, sv_ti.x);                      \
            d[1] = make_float2(sv_tr.y, sv_ti.y);                      \
            d[2] = make_float2(sv_tr.z, sv_ti.z);                      \
            d[3] = make_float2(sv_tr.w, sv_ti.w);                      \
        }                                                              \
        if (lane < 50) {                                               \
            float2* d = (float2*)(W + 200) + lane * 4;                 \
            d[0] = make_float2(sv_ar.x, sv_ai.x);                      \
            d[1] = make_float2(sv_ar.y, sv_ai.y);                      \
            d[2] = make_float2(sv_ar.z, sv_ai.z);                      \
            d[3] = make_float2(sv_ar.w, sv_ai.w);                      \
            d = (float2*)(W + 600) + lane * 4;                         \
            d[0] = make_float2(sv_br.x, sv_bi.x);                      \
            d[1] = make_float2(sv_br.y, sv_bi.y);                      \
            d[2] = make_float2(sv_br.z, sv_bi.z);                      \
            d[3] = make_float2(sv_br.w, sv_bi.w);                      \
        }                                                              \
        if (lane < 16) ((float4*)(W + 1000))[lane] = sv_f;             \
    }

    const long bbase = (long)blockIdx.x * 16 + (long)wave * 4;
    STAGE_LOAD(bbase);
    STAGE_WRITE();   // dep-waits on the staged regs, then LDS writes

    for (int it = 0; it < 4; ++it) {
        // staged LDS writes must be visible before this it's reads
        asm volatile("s_waitcnt lgkmcnt(0)" ::: "memory");
        __builtin_amdgcn_wave_barrier();

        // issue next iteration's staging loads NOW; they fly during compute
        if (it < 3) STAGE_LOAD(bbase + it + 1);

        const float* urb = Ur + (bbase + it) * 800;
        const float* uib = Ui + (bbase + it) * 800;

        // phi partials: [0,1]=phi1 n0 re/im, [2,3]=phi1 n1, [4,5]=phi2 n0, [6,7]=phi2 n1
        float p[8] = {0,0,0,0,0,0,0,0};

        // U stream, 4-deep register prefetch (issue-early / use-late).
        #define LDU(s) make_float2(urb[(s)*64 + lane], uib[(s)*64 + lane])
        #define CBODY(k, u) {                                        \
            float2 th = *(const float2*)(W + 2*(k));                 \
            float2 a  = *(const float2*)(W + 200 + 2*(k));           \
            float2 c  = *(const float2*)(W + 400 + 2*(k));           \
            float2 d2 = *(const float2*)(W + 600 + 2*(k));           \
            float2 e2 = *(const float2*)(W + 800 + 2*(k));           \
            float wr = th.x*(u).x - th.y*(u).y;                      \
            float wi = th.x*(u).y + th.y*(u).x;                      \
            p[0] += a.x*wr  - a.y*wi;   p[1] += a.x*wi  + a.y*wr;    \
            p[2] += c.x*wr  - c.y*wi;   p[3] += c.x*wi  + c.y*wr;    \
            p[4] += d2.x*wr - d2.y*wi;  p[5] += d2.x*wi + d2.y*wr;   \
            p[6] += e2.x*wr - e2.y*wi;  p[7] += e2.x*wi + e2.y*wr; }

        float2 u0 = LDU(0), u1 = LDU(1), u2 = LDU(2), u3 = LDU(3);
        const int ctail = 768 + (lane < 32 ? lane : 31);  // clamped tail offset
        #pragma unroll 1   // rolled: keep VGPR low; prefetch provides the ILP
        for (int g = 0; g < 3; ++g) {
            const int s = 4 * g;
            float2 n0, n1, n2, n3;
            if (g < 2) {
                n0 = LDU(s + 4); n1 = LDU(s + 5);
                n2 = LDU(s + 6); n3 = LDU(s + 7);
            } else {
                n0 = make_float2(urb[ctail], uib[ctail]);  // strip 12 (masked later)
                n1 = n2 = n3 = n0;
            }
            CBODY(8*s + k0,      u0);
            CBODY(8*s + 8 + k0,  u1);
            CBODY(8*s + 16 + k0, u2);
            CBODY(8*s + 24 + k0, u3);
            u0 = n0; u1 = n1; u2 = n2; u3 = n3;
        }
        if (k0 < 4) {
            CBODY(96 + k0, u0);  // tail strip 12
        }
        #undef LDU
        #undef CBODY

        // reduce over the 8 k-strips (lane bits 3..5): stages 8 and 32 on all 8
        // partials, then exchange-then-add on bit 4 (keep nn, send 1-nn).
        #pragma unroll
        for (int q = 0; q < 8; ++q) {
            p[q] += __shfl_xor(p[q], 8);
            p[q] += __shfl_xor(p[q], 32);
        }
        float4 ph;
        {
            float k0r = nn ? p[2] : p[0], s0r = nn ? p[0] : p[2];
            float k0i = nn ? p[3] : p[1], s0i = nn ? p[1] : p[3];
            float k1r = nn ? p[6] : p[4], s1r = nn ? p[4] : p[6];
            float k1i = nn ? p[7] : p[5], s1i = nn ? p[5] : p[7];
            ph.x = k0r + __shfl_xor(s0r, 16);
            ph.y = k0i + __shfl_xor(s0i, 16);
            ph.z = k1r + __shfl_xor(s1r, 16);
            ph.w = k1i + __shfl_xor(s1i, 16);
        }

        // ---- F norms: scale_h = sqrt(2 / sum|F_h|^2) ----  (F from LDS)
        float s1, s2;
        {
            int idx = lane & 15;
            int sel = (lane >> 4) & 1;
            float fr = W[1000 + sel*32 + idx];
            float fi = W[1016 + sel*32 + idx];
            float m = fr*fr + fi*fi;
            #pragma unroll
            for (int s = 1; s < 16; s <<= 1) m += __shfl_xor(m, s);
            float other = __shfl_xor(m, 16);
            float nrm1 = sel ? other : m;
            float nrm2 = sel ? m : other;
            s1 = sqrtf(2.0f / nrm1);
            s2 = sqrtf(2.0f / nrm2);
        }

        // ---- A/C entries: ent[it][0..7] = {A,C} for R1; [8..15] for R2 ----
        {
            int jf = t*2 + rr;
            float2 f1 = make_float2(W[1000 + jf], W[1016 + jf]);
            float2 f2 = make_float2(W[1032 + jf], W[1048 + jf]);
            float2 phi1n = make_float2(ph.x, ph.y);
            float2 phi2n = make_float2(ph.z, ph.w);
            bool lo = (e8 < 4);
            float2 E0 = cmul(phi1n, lo ? f1 : f2);
            float2 E1 = cmul(phi2n, lo ? f2 : f1);
            #pragma unroll
            for (int s = 1; s < 8; s <<= 1) {
                E0.x += __shfl_xor(E0.x, s); E0.y += __shfl_xor(E0.y, s);
                E1.x += __shfl_xor(E1.x, s); E1.y += __shfl_xor(E1.y, s);
            }
            if (t == 0) {
                ent[wave][it][e8]     = cscale(lo ? s1 : s2, E0);
                ent[wave][it][e8 + 8] = cscale(lo ? s2 : s1, E1);
            }
        }

        // write next it's staged data into LDS after this it's reads drained
        if (it < 3) {
            asm volatile("s_waitcnt lgkmcnt(0)" ::: "memory");
            __builtin_amdgcn_wave_barrier();
            STAGE_WRITE();
        }
    }
    #undef STAGE_LOAD
    #undef STAGE_WRITE
    asm volatile("s_waitcnt lgkmcnt(0)" ::: "memory");
    __builtin_amdgcn_wave_barrier();

    // ---- batched 2x2 complex rate: lanes 0..7 -> (it = lane>>1, R1/R2 = lane&1) ----
    float negR = 0.0f;
    if (lane < 8) {
        const float2* e = &ent[wave][lane >> 1][(lane & 1) * 8];
        float2 A00=e[0], A01=e[1], A10=e[2], A11=e[3];
        float2 C00=e[4], C01=e[5], C10=e[6], C11=e[7];
        float mu00 = C00.x*C00.x + C00.y*C00.y + C01.x*C01.x + C01.y*C01.y + NOISE;
        float mu11 = C10.x*C10.x + C10.y*C10.y + C11.x*C11.x + C11.y*C11.y + NOISE;
        float2 mu01 = cadd(cmulconj(C00, C10), cmulconj(C01, C11));
        mu01.x += NOISE;
        float det = mu00*mu11 - (mu01.x*mu01.x + mu01.y*mu01.y);
        float inv = 1.0f / det;
        float2 mu01c = make_float2(mu01.x, -mu01.y);
        float2 X00 = cscale(inv, csub(cscale(mu11, A00), cmul(mu01,  A10)));
        float2 X01 = cscale(inv, csub(cscale(mu11, A01), cmul(mu01,  A11)));
        float2 X10 = cscale(inv, csub(cscale(mu00, A10), cmul(mu01c, A00)));
        float2 X11 = cscale(inv, csub(cscale(mu00, A11), cmul(mu01c, A01)));
        float2 I00 = cadd(cconjmul(A00, X00), cconjmul(A10, X10));
        float2 I01 = cadd(cconjmul(A00, X01), cconjmul(A10, X11));
        float2 I10 = cadd(cconjmul(A01, X00), cconjmul(A11, X10));
        float2 I11 = cadd(cconjmul(A01, X01), cconjmul(A11, X11));
        I00.x += 1.0f; I01.x += 1.0f; I10.x += 1.0f; I11.x += 1.0f;
        float2 dT = csub(cmul(I00, I11), cmul(I01, I10));
        negR = -0.5f * logf(dT.x*dT.x + dT.y*dT.y);  // -Re(log z) = -ln|z|
    }
    // pairwise max over (R1,R2), then sum the 4 batch elements
    float m = fmaxf(negR, __shfl_xor(negR, 1));
    m += __shfl_xor(m, 2);
    m += __shfl_xor(m, 4);
    if (lane == 0) wsum[wave] = m;

    __syncthreads();
    if (threadIdx.x == 0)
        partial[blockIdx.x] = (wsum[0] + wsum[1]) + (wsum[2] + wsum[3]);
}

__global__ __launch_bounds__(256) void reduce_kernel(
    const float* __restrict__ partial, int n, float invB, float* __restrict__ out)
{
    __shared__ float sd[256];
    float s = 0.0f;
    for (int i = threadIdx.x; i < n; i += 256) s += partial[i];
    sd[threadIdx.x] = s;
    __syncthreads();
    for (int o = 128; o > 0; o >>= 1) {
        if ((int)threadIdx.x < o) sd[threadIdx.x] += sd[threadIdx.x + o];
        __syncthreads();
    }
    if (threadIdx.x == 0) out[0] = sd[0] * invB;
}

extern "C" void kernel_launch(void* const* d_in, const int* in_sizes, int n_in,
                              void* d_out, int out_size, void* d_ws, size_t ws_size,
                              hipStream_t stream) {
    const float* t1  = (const float*)d_in[0];
    const float* G1r = (const float*)d_in[1];
    const float* G1i = (const float*)d_in[2];
    const float* G2r = (const float*)d_in[3];
    const float* G2i = (const float*)d_in[4];
    const float* Ur  = (const float*)d_in[5];
    const float* Ui  = (const float*)d_in[6];

    const int B = in_sizes[0] / 264;        // 65536
    const int nblocks = B / 16;             // 16 batch elements per block
    float* partial = (float*)d_ws;          // nblocks floats

    rate_kernel<<<nblocks, 256, 0, stream>>>(t1, G1r, G1i, G2r, G2i, Ur, Ui, partial);
    reduce_kernel<<<1, 256, 0, stream>>>(partial, nblocks, 1.0f / (float)B, (float*)d_out);
}

// Round 9
// 144.793 us; speedup vs baseline: 1.0376x; 1.0376x over previous
//
#include <hip/hip_runtime.h>
#include <math.h>

#define NOISE 1e-12f
#define WSZ 1064   // per-wave LDS floats per buffer: T(264) | G1r(200) | G1i(200) | G2r(200) | G2i(200)

__device__ __forceinline__ float2 cmul(float2 a, float2 b) {
    return make_float2(a.x*b.x - a.y*b.y, a.x*b.y + a.y*b.x);
}
// conj(a)*b
__device__ __forceinline__ float2 cconjmul(float2 a, float2 b) {
    return make_float2(a.x*b.x + a.y*b.y, a.x*b.y - a.y*b.x);
}
// a*conj(b)
__device__ __forceinline__ float2 cmulconj(float2 a, float2 b) {
    return make_float2(a.x*b.x + a.y*b.y, a.y*b.x - a.x*b.y);
}
__device__ __forceinline__ float2 cadd(float2 a, float2 b){ return make_float2(a.x+b.x, a.y+b.y); }
__device__ __forceinline__ float2 csub(float2 a, float2 b){ return make_float2(a.x-b.x, a.y-b.y); }
__device__ __forceinline__ float2 cscale(float s, float2 a){ return make_float2(s*a.x, s*a.y); }

// async global->LDS, 16 B per lane (fire-and-forget; counted by vmcnt)
typedef const void __attribute__((address_space(1)))* gas_t;
typedef void __attribute__((address_space(3)))* las_t;
__device__ __forceinline__ void gll16(const float* g, float* l) {
    __builtin_amdgcn_global_load_lds((gas_t)g, (las_t)l, 16, 0, 0);
}

// one wave per batch element iteration; 4 waves/block; 4 iterations -> 16 b per block
__global__ __launch_bounds__(256) void rate_kernel(
    const float* __restrict__ t1,
    const float* __restrict__ G1r, const float* __restrict__ G1i,
    const float* __restrict__ G2r, const float* __restrict__ G2i,
    const float* __restrict__ Ur,  const float* __restrict__ Ui,
    float* __restrict__ partial)
{
    __shared__ float lds[4 * 2 * WSZ];  // per-wave double-buffered staging
    __shared__ float2 ent[4][4][16];    // [wave][it][entry]
    __shared__ float wsum[4];
    const int wave = threadIdx.x >> 6;
    const int lane = threadIdx.x & 63;
    const int t  = lane & 7;     // output column of phi
    const int k0 = lane >> 3;    // k-strip (k = 8j + k0), reused as entry-octet id
    const int e8 = k0;
    const int nn = (e8 >> 1) & 1;   // = lane bit 4
    const int rr = e8 & 1;
    float* Wbuf = lds + wave * 2 * WSZ;

    // stage b's theta/G/F row into LDS buffer `dst` (6 vmcnt-counted issues)
    #define STAGE(dst, bb) {                                                  \
        const float* tb_ = t1 + (long)(bb) * 264;                             \
        gll16(tb_ + lane * 4, (dst));                 /* T[0..255]   */       \
        if (lane < 2)  gll16(tb_ + 256 + lane * 4, (dst) + 256);              \
        if (lane < 50) {                                                      \
            gll16(G1r + (long)(bb) * 200 + lane * 4, (dst) + 264);            \
            gll16(G1i + (long)(bb) * 200 + lane * 4, (dst) + 464);            \
            gll16(G2r + (long)(bb) * 200 + lane * 4, (dst) + 664);            \
            gll16(G2i + (long)(bb) * 200 + lane * 4, (dst) + 864);            \
        }                                                                     \
    }

    const long bbase = (long)blockIdx.x * 16 + (long)wave * 4;
    STAGE(Wbuf, bbase);   // prologue: buffer 0 for it 0

    for (int it = 0; it < 4; ++it) {
        float* W = Wbuf + (it & 1) * WSZ;

        // issue next it's staging first (flies under this it's compute),
        // then counted wait: all OLDER (current-buffer) staging complete.
        if (it < 3) {
            STAGE(Wbuf + ((it + 1) & 1) * WSZ, bbase + it + 1);
            asm volatile("s_waitcnt vmcnt(6)" ::: "memory");
        } else {
            asm volatile("s_waitcnt vmcnt(0)" ::: "memory");
        }
        __builtin_amdgcn_sched_barrier(0);

        const float* urb = Ur + (bbase + it) * 800;
        const float* uib = Ui + (bbase + it) * 800;

        // phi partials: [0,1]=phi1 n0 re/im, [2,3]=phi1 n1, [4,5]=phi2 n0, [6,7]=phi2 n1
        float p[8] = {0,0,0,0,0,0,0,0};

        // U stream, 4-deep register prefetch (issue-early / use-late).
        #define LDU(s) make_float2(urb[(s)*64 + lane], uib[(s)*64 + lane])
        #define CBODY(k, u) {                                        \
            float thr = W[(k)],      thi = W[100 + (k)];             \
            float2 a  = make_float2(W[264 + (k)], W[464 + (k)]);     \
            float2 c  = make_float2(W[364 + (k)], W[564 + (k)]);     \
            float2 d2 = make_float2(W[664 + (k)], W[864 + (k)]);     \
            float2 e2 = make_float2(W[764 + (k)], W[964 + (k)]);     \
            float wr = thr*(u).x - thi*(u).y;                        \
            float wi = thr*(u).y + thi*(u).x;                        \
            p[0] += a.x*wr  - a.y*wi;   p[1] += a.x*wi  + a.y*wr;    \
            p[2] += c.x*wr  - c.y*wi;   p[3] += c.x*wi  + c.y*wr;    \
            p[4] += d2.x*wr - d2.y*wi;  p[5] += d2.x*wi + d2.y*wr;   \
            p[6] += e2.x*wr - e2.y*wi;  p[7] += e2.x*wi + e2.y*wr; }

        float2 u0 = LDU(0), u1 = LDU(1), u2 = LDU(2), u3 = LDU(3);
        const int ctail = 768 + (lane < 32 ? lane : 31);  // clamped tail offset
        #pragma unroll 1   // rolled: keep VGPR low; prefetch provides the ILP
        for (int g = 0; g < 3; ++g) {
            const int s = 4 * g;
            float2 n0, n1, n2, n3;
            if (g < 2) {
                n0 = LDU(s + 4); n1 = LDU(s + 5);
                n2 = LDU(s + 6); n3 = LDU(s + 7);
            } else {
                n0 = make_float2(urb[ctail], uib[ctail]);  // strip 12 (masked later)
                n1 = n2 = n3 = n0;
            }
            CBODY(8*s + k0,      u0);
            CBODY(8*s + 8 + k0,  u1);
            CBODY(8*s + 16 + k0, u2);
            CBODY(8*s + 24 + k0, u3);
            u0 = n0; u1 = n1; u2 = n2; u3 = n3;
        }
        if (k0 < 4) {
            CBODY(96 + k0, u0);  // tail strip 12
        }
        #undef LDU
        #undef CBODY

        // reduce over the 8 k-strips (lane bits 3..5): stages 8 and 32 on all 8
        // partials, then exchange-then-add on bit 4 (keep nn, send 1-nn).
        #pragma unroll
        for (int q = 0; q < 8; ++q) {
            p[q] += __shfl_xor(p[q], 8);
            p[q] += __shfl_xor(p[q], 32);
        }
        float4 ph;
        {
            float k0r = nn ? p[2] : p[0], s0r = nn ? p[0] : p[2];
            float k0i = nn ? p[3] : p[1], s0i = nn ? p[1] : p[3];
            float k1r = nn ? p[6] : p[4], s1r = nn ? p[4] : p[6];
            float k1i = nn ? p[7] : p[5], s1i = nn ? p[5] : p[7];
            ph.x = k0r + __shfl_xor(s0r, 16);
            ph.y = k0i + __shfl_xor(s0i, 16);
            ph.z = k1r + __shfl_xor(s1r, 16);
            ph.w = k1i + __shfl_xor(s1i, 16);
        }

        // ---- F norms: scale_h = sqrt(2 / sum|F_h|^2) ----  (F from LDS T region)
        float s1, s2;
        {
            int idx = lane & 15;
            int sel = (lane >> 4) & 1;
            float fr = W[200 + sel*32 + idx];
            float fi = W[216 + sel*32 + idx];
            float m = fr*fr + fi*fi;
            #pragma unroll
            for (int s = 1; s < 16; s <<= 1) m += __shfl_xor(m, s);
            float other = __shfl_xor(m, 16);
            float nrm1 = sel ? other : m;
            float nrm2 = sel ? m : other;
            s1 = sqrtf(2.0f / nrm1);
            s2 = sqrtf(2.0f / nrm2);
        }

        // ---- A/C entries: ent[it][0..7] = {A,C} for R1; [8..15] for R2 ----
        {
            int jf = t*2 + rr;
            float2 f1 = make_float2(W[200 + jf], W[216 + jf]);
            float2 f2 = make_float2(W[232 + jf], W[248 + jf]);
            float2 phi1n = make_float2(ph.x, ph.y);
            float2 phi2n = make_float2(ph.z, ph.w);
            bool lo = (e8 < 4);
            float2 E0 = cmul(phi1n, lo ? f1 : f2);
            float2 E1 = cmul(phi2n, lo ? f2 : f1);
            #pragma unroll
            for (int s = 1; s < 8; s <<= 1) {
                E0.x += __shfl_xor(E0.x, s); E0.y += __shfl_xor(E0.y, s);
                E1.x += __shfl_xor(E1.x, s); E1.y += __shfl_xor(E1.y, s);
            }
            if (t == 0) {
                ent[wave][it][e8]     = cscale(lo ? s1 : s2, E0);
                ent[wave][it][e8 + 8] = cscale(lo ? s2 : s1, E1);
            }
        }
    }
    #undef STAGE
    asm volatile("s_waitcnt lgkmcnt(0)" ::: "memory");
    __builtin_amdgcn_wave_barrier();

    // ---- batched 2x2 complex rate: lanes 0..7 -> (it = lane>>1, R1/R2 = lane&1) ----
    float negR = 0.0f;
    if (lane < 8) {
        const float2* e = &ent[wave][lane >> 1][(lane & 1) * 8];
        float2 A00=e[0], A01=e[1], A10=e[2], A11=e[3];
        float2 C00=e[4], C01=e[5], C10=e[6], C11=e[7];
        float mu00 = C00.x*C00.x + C00.y*C00.y + C01.x*C01.x + C01.y*C01.y + NOISE;
        float mu11 = C10.x*C10.x + C10.y*C10.y + C11.x*C11.x + C11.y*C11.y + NOISE;
        float2 mu01 = cadd(cmulconj(C00, C10), cmulconj(C01, C11));
        mu01.x += NOISE;
        float det = mu00*mu11 - (mu01.x*mu01.x + mu01.y*mu01.y);
        float inv = 1.0f / det;
        float2 mu01c = make_float2(mu01.x, -mu01.y);
        float2 X00 = cscale(inv, csub(cscale(mu11, A00), cmul(mu01,  A10)));
        float2 X01 = cscale(inv, csub(cscale(mu11, A01), cmul(mu01,  A11)));
        float2 X10 = cscale(inv, csub(cscale(mu00, A10), cmul(mu01c, A00)));
        float2 X11 = cscale(inv, csub(cscale(mu00, A11), cmul(mu01c, A01)));
        float2 I00 = cadd(cconjmul(A00, X00), cconjmul(A10, X10));
        float2 I01 = cadd(cconjmul(A00, X01), cconjmul(A10, X11));
        float2 I10 = cadd(cconjmul(A01, X00), cconjmul(A11, X10));
        float2 I11 = cadd(cconjmul(A01, X01), cconjmul(A11, X11));
        I00.x += 1.0f; I01.x += 1.0f; I10.x += 1.0f; I11.x += 1.0f;
        float2 dT = csub(cmul(I00, I11), cmul(I01, I10));
        negR = -0.5f * logf(dT.x*dT.x + dT.y*dT.y);  // -Re(log z) = -ln|z|
    }
    // pairwise max over (R1,R2), then sum the 4 batch elements
    float m = fmaxf(negR, __shfl_xor(negR, 1));
    m += __shfl_xor(m, 2);
    m += __shfl_xor(m, 4);
    if (lane == 0) wsum[wave] = m;

    __syncthreads();
    if (threadIdx.x == 0)
        partial[blockIdx.x] = (wsum[0] + wsum[1]) + (wsum[2] + wsum[3]);
}

__global__ __launch_bounds__(256) void reduce_kernel(
    const float* __restrict__ partial, int n, float invB, float* __restrict__ out)
{
    __shared__ float sd[256];
    float s = 0.0f;
    for (int i = threadIdx.x; i < n; i += 256) s += partial[i];
    sd[threadIdx.x] = s;
    __syncthreads();
    for (int o = 128; o > 0; o >>= 1) {
        if ((int)threadIdx.x < o) sd[threadIdx.x] += sd[threadIdx.x + o];
        __syncthreads();
    }
    if (threadIdx.x == 0) out[0] = sd[0] * invB;
}

extern "C" void kernel_launch(void* const* d_in, const int* in_sizes, int n_in,
                              void* d_out, int out_size, void* d_ws, size_t ws_size,
                              hipStream_t stream) {
    const float* t1  = (const float*)d_in[0];
    const float* G1r = (const float*)d_in[1];
    const float* G1i = (const float*)d_in[2];
    const float* G2r = (const float*)d_in[3];
    const float* G2i = (const float*)d_in[4];
    const float* Ur  = (const float*)d_in[5];
    const float* Ui  = (const float*)d_in[6];

    const int B = in_sizes[0] / 264;        // 65536
    const int nblocks = B / 16;             // 16 batch elements per block
    float* partial = (float*)d_ws;          // nblocks floats

    rate_kernel<<<nblocks, 256, 0, stream>>>(t1, G1r, G1i, G2r, G2i, Ur, Ui, partial);
    reduce_kernel<<<1, 256, 0, stream>>>(partial, nblocks, 1.0f / (float)B, (float*)d_out);
}

// Round 10
// 143.591 us; speedup vs baseline: 1.0463x; 1.0084x over previous
//
#include <hip/hip_runtime.h>
#include <math.h>

#define NOISE 1e-12f
#define WSZ 1064   // per-wave LDS floats per buffer: T(264) | G1r(200) | G1i(200) | G2r(200) | G2i(200)

__device__ __forceinline__ float2 cmul(float2 a, float2 b) {
    return make_float2(a.x*b.x - a.y*b.y, a.x*b.y + a.y*b.x);
}
// conj(a)*b
__device__ __forceinline__ float2 cconjmul(float2 a, float2 b) {
    return make_float2(a.x*b.x + a.y*b.y, a.x*b.y - a.y*b.x);
}
// a*conj(b)
__device__ __forceinline__ float2 cmulconj(float2 a, float2 b) {
    return make_float2(a.x*b.x + a.y*b.y, a.y*b.x - a.x*b.y);
}
__device__ __forceinline__ float2 cadd(float2 a, float2 b){ return make_float2(a.x+b.x, a.y+b.y); }
__device__ __forceinline__ float2 csub(float2 a, float2 b){ return make_float2(a.x-b.x, a.y-b.y); }
__device__ __forceinline__ float2 cscale(float s, float2 a){ return make_float2(s*a.x, s*a.y); }

// async global->LDS, 16 B per lane (fire-and-forget; counted by vmcnt)
typedef const void __attribute__((address_space(1)))* gas_t;
typedef void __attribute__((address_space(3)))* las_t;
__device__ __forceinline__ void gll16(const float* g, float* l) {
    __builtin_amdgcn_global_load_lds((gas_t)g, (las_t)l, 16, 0, 0);
}

// one wave per batch element iteration; 4 waves/block; 4 iterations -> 16 b per block
__global__ __launch_bounds__(256) void rate_kernel(
    const float* __restrict__ t1,
    const float* __restrict__ G1r, const float* __restrict__ G1i,
    const float* __restrict__ G2r, const float* __restrict__ G2i,
    const float* __restrict__ Ur,  const float* __restrict__ Ui,
    float* __restrict__ partial)
{
    __shared__ float lds[4 * 2 * WSZ];  // per-wave double-buffered staging
    __shared__ float2 ent[4][4][16];    // [wave][it][entry]
    __shared__ float wsum[4];
    const int wave = threadIdx.x >> 6;
    const int lane = threadIdx.x & 63;
    const int t  = lane & 7;     // output column of phi
    const int k0 = lane >> 3;    // k-strip (k = 8j + k0), reused as entry-octet id
    const int e8 = k0;
    const int nn = (e8 >> 1) & 1;   // = lane bit 4
    const int rr = e8 & 1;
    float* Wbuf = lds + wave * 2 * WSZ;

    // stage b's theta/G/F row into LDS buffer `dst` (6 vmcnt-counted issues)
    #define STAGE(dst, bb) {                                                  \
        const float* tb_ = t1 + (long)(bb) * 264;                             \
        gll16(tb_ + lane * 4, (dst));                 /* T[0..255]   */       \
        if (lane < 2)  gll16(tb_ + 256 + lane * 4, (dst) + 256);              \
        if (lane < 50) {                                                      \
            gll16(G1r + (long)(bb) * 200 + lane * 4, (dst) + 264);            \
            gll16(G1i + (long)(bb) * 200 + lane * 4, (dst) + 464);            \
            gll16(G2r + (long)(bb) * 200 + lane * 4, (dst) + 664);            \
            gll16(G2i + (long)(bb) * 200 + lane * 4, (dst) + 864);            \
        }                                                                     \
    }

    const long bbase = (long)blockIdx.x * 16 + (long)wave * 4;
    STAGE(Wbuf, bbase);   // prologue: buffer 0 for it 0

    const float* urb = Ur + bbase * 800;
    const float* uib = Ui + bbase * 800;
    #define LDU(s) make_float2(urb[(s)*64 + lane], uib[(s)*64 + lane])

    // initial U prefetch for it 0 (strips 0..3)
    float2 u0 = LDU(0), u1 = LDU(1), u2 = LDU(2), u3 = LDU(3);

    for (int it = 0; it < 4; ++it) {
        float* W = Wbuf + (it & 1) * WSZ;

        // issue next it's staging first (flies under this it's compute).
        // Outstanding at the wait: [8 prefetched U][6 new gll] = 14, so
        // vmcnt(14) drains exactly the CURRENT buffer's staging at it0; at
        // it1/2 the current buffer is already guaranteed by in-order
        // retirement through it-1's consumed U loads (wait is a no-op).
        if (it < 3) {
            STAGE(Wbuf + ((it + 1) & 1) * WSZ, bbase + it + 1);
            asm volatile("s_waitcnt vmcnt(14)" ::: "memory");
        }
        __builtin_amdgcn_sched_barrier(0);

        // phi partials: [0,1]=phi1 n0 re/im, [2,3]=phi1 n1, [4,5]=phi2 n0, [6,7]=phi2 n1
        float p[8] = {0,0,0,0,0,0,0,0};

        #define CBODY(k, u) {                                        \
            float thr = W[(k)],      thi = W[100 + (k)];             \
            float2 a  = make_float2(W[264 + (k)], W[464 + (k)]);     \
            float2 c  = make_float2(W[364 + (k)], W[564 + (k)]);     \
            float2 d2 = make_float2(W[664 + (k)], W[864 + (k)]);     \
            float2 e2 = make_float2(W[764 + (k)], W[964 + (k)]);     \
            float wr = thr*(u).x - thi*(u).y;                        \
            float wi = thr*(u).y + thi*(u).x;                        \
            p[0] += a.x*wr  - a.y*wi;   p[1] += a.x*wi  + a.y*wr;    \
            p[2] += c.x*wr  - c.y*wi;   p[3] += c.x*wi  + c.y*wr;    \
            p[4] += d2.x*wr - d2.y*wi;  p[5] += d2.x*wi + d2.y*wr;   \
            p[6] += e2.x*wr - e2.y*wi;  p[7] += e2.x*wi + e2.y*wr; }

        const int ctail = 768 + (lane < 32 ? lane : 31);  // clamped tail offset
        #pragma unroll 1   // rolled: keep VGPR low; prefetch provides the ILP
        for (int g = 0; g < 3; ++g) {
            const int s = 4 * g;
            float2 n0, n1, n2, n3;
            if (g < 2) {
                n0 = LDU(s + 4); n1 = LDU(s + 5);
                n2 = LDU(s + 6); n3 = LDU(s + 7);
            } else {
                n0 = make_float2(urb[ctail], uib[ctail]);  // strip 12 (masked later)
                n1 = n2 = n3 = n0;
            }
            CBODY(8*s + k0,      u0);
            CBODY(8*s + 8 + k0,  u1);
            CBODY(8*s + 16 + k0, u2);
            CBODY(8*s + 24 + k0, u3);
            u0 = n0; u1 = n1; u2 = n2; u3 = n3;
        }
        if (k0 < 4) {
            CBODY(96 + k0, u0);  // tail strip 12
        }
        #undef CBODY

        // cross-it U prefetch: issue next it's strips 0..3 NOW; the shuffle
        // phase below (~15 serial cross-lane ops) covers their latency.
        if (it < 3) {
            urb += 800; uib += 800;
            u0 = LDU(0); u1 = LDU(1); u2 = LDU(2); u3 = LDU(3);
        }

        // reduce over the 8 k-strips (lane bits 3..5): stages 8 and 32 on all 8
        // partials, then exchange-then-add on bit 4 (keep nn, send 1-nn).
        #pragma unroll
        for (int q = 0; q < 8; ++q) {
            p[q] += __shfl_xor(p[q], 8);
            p[q] += __shfl_xor(p[q], 32);
        }
        float4 ph;
        {
            float k0r = nn ? p[2] : p[0], s0r = nn ? p[0] : p[2];
            float k0i = nn ? p[3] : p[1], s0i = nn ? p[1] : p[3];
            float k1r = nn ? p[6] : p[4], s1r = nn ? p[4] : p[6];
            float k1i = nn ? p[7] : p[5], s1i = nn ? p[5] : p[7];
            ph.x = k0r + __shfl_xor(s0r, 16);
            ph.y = k0i + __shfl_xor(s0i, 16);
            ph.z = k1r + __shfl_xor(s1r, 16);
            ph.w = k1i + __shfl_xor(s1i, 16);
        }

        // ---- F norms: scale_h = sqrt(2 / sum|F_h|^2) ----  (F from LDS T region)
        float s1, s2;
        {
            int idx = lane & 15;
            int sel = (lane >> 4) & 1;
            float fr = W[200 + sel*32 + idx];
            float fi = W[216 + sel*32 + idx];
            float m = fr*fr + fi*fi;
            #pragma unroll
            for (int s = 1; s < 16; s <<= 1) m += __shfl_xor(m, s);
            float other = __shfl_xor(m, 16);
            float nrm1 = sel ? other : m;
            float nrm2 = sel ? m : other;
            s1 = sqrtf(2.0f / nrm1);
            s2 = sqrtf(2.0f / nrm2);
        }

        // ---- A/C entries: ent[it][0..7] = {A,C} for R1; [8..15] for R2 ----
        {
            int jf = t*2 + rr;
            float2 f1 = make_float2(W[200 + jf], W[216 + jf]);
            float2 f2 = make_float2(W[232 + jf], W[248 + jf]);
            float2 phi1n = make_float2(ph.x, ph.y);
            float2 phi2n = make_float2(ph.z, ph.w);
            bool lo = (e8 < 4);
            float2 E0 = cmul(phi1n, lo ? f1 : f2);
            float2 E1 = cmul(phi2n, lo ? f2 : f1);
            #pragma unroll
            for (int s = 1; s < 8; s <<= 1) {
                E0.x += __shfl_xor(E0.x, s); E0.y += __shfl_xor(E0.y, s);
                E1.x += __shfl_xor(E1.x, s); E1.y += __shfl_xor(E1.y, s);
            }
            if (t == 0) {
                ent[wave][it][e8]     = cscale(lo ? s1 : s2, E0);
                ent[wave][it][e8 + 8] = cscale(lo ? s2 : s1, E1);
            }
        }
    }
    #undef STAGE
    #undef LDU
    asm volatile("s_waitcnt lgkmcnt(0)" ::: "memory");
    __builtin_amdgcn_wave_barrier();

    // ---- batched 2x2 complex rate: lanes 0..7 -> (it = lane>>1, R1/R2 = lane&1) ----
    float negR = 0.0f;
    if (lane < 8) {
        const float2* e = &ent[wave][lane >> 1][(lane & 1) * 8];
        float2 A00=e[0], A01=e[1], A10=e[2], A11=e[3];
        float2 C00=e[4], C01=e[5], C10=e[6], C11=e[7];
        float mu00 = C00.x*C00.x + C00.y*C00.y + C01.x*C01.x + C01.y*C01.y + NOISE;
        float mu11 = C10.x*C10.x + C10.y*C10.y + C11.x*C11.x + C11.y*C11.y + NOISE;
        float2 mu01 = cadd(cmulconj(C00, C10), cmulconj(C01, C11));
        mu01.x += NOISE;
        float det = mu00*mu11 - (mu01.x*mu01.x + mu01.y*mu01.y);
        float inv = 1.0f / det;
        float2 mu01c = make_float2(mu01.x, -mu01.y);
        float2 X00 = cscale(inv, csub(cscale(mu11, A00), cmul(mu01,  A10)));
        float2 X01 = cscale(inv, csub(cscale(mu11, A01), cmul(mu01,  A11)));
        float2 X10 = cscale(inv, csub(cscale(mu00, A10), cmul(mu01c, A00)));
        float2 X11 = cscale(inv, csub(cscale(mu00, A11), cmul(mu01c, A01)));
        float2 I00 = cadd(cconjmul(A00, X00), cconjmul(A10, X10));
        float2 I01 = cadd(cconjmul(A00, X01), cconjmul(A10, X11));
        float2 I10 = cadd(cconjmul(A01, X00), cconjmul(A11, X10));
        float2 I11 = cadd(cconjmul(A01, X01), cconjmul(A11, X11));
        I00.x += 1.0f; I01.x += 1.0f; I10.x += 1.0f; I11.x += 1.0f;
        float2 dT = csub(cmul(I00, I11), cmul(I01, I10));
        negR = -0.5f * logf(dT.x*dT.x + dT.y*dT.y);  // -Re(log z) = -ln|z|
    }
    // pairwise max over (R1,R2), then sum the 4 batch elements
    float m = fmaxf(negR, __shfl_xor(negR, 1));
    m += __shfl_xor(m, 2);
    m += __shfl_xor(m, 4);
    if (lane == 0) wsum[wave] = m;

    __syncthreads();
    if (threadIdx.x == 0)
        partial[blockIdx.x] = (wsum[0] + wsum[1]) + (wsum[2] + wsum[3]);
}

__global__ __launch_bounds__(256) void reduce_kernel(
    const float* __restrict__ partial, int n, float invB, float* __restrict__ out)
{
    __shared__ float sd[256];
    float s = 0.0f;
    for (int i = threadIdx.x; i < n; i += 256) s += partial[i];
    sd[threadIdx.x] = s;
    __syncthreads();
    for (int o = 128; o > 0; o >>= 1) {
        if ((int)threadIdx.x < o) sd[threadIdx.x] += sd[threadIdx.x + o];
        __syncthreads();
    }
    if (threadIdx.x == 0) out[0] = sd[0] * invB;
}

extern "C" void kernel_launch(void* const* d_in, const int* in_sizes, int n_in,
                              void* d_out, int out_size, void* d_ws, size_t ws_size,
                              hipStream_t stream) {
    const float* t1  = (const float*)d_in[0];
    const float* G1r = (const float*)d_in[1];
    const float* G1i = (const float*)d_in[2];
    const float* G2r = (const float*)d_in[3];
    const float* G2i = (const float*)d_in[4];
    const float* Ur  = (const float*)d_in[5];
    const float* Ui  = (const float*)d_in[6];

    const int B = in_sizes[0] / 264;        // 65536
    const int nblocks = B / 16;             // 16 batch elements per block
    float* partial = (float*)d_ws;          // nblocks floats

    rate_kernel<<<nblocks, 256, 0, stream>>>(t1, G1r, G1i, G2r, G2i, Ur, Ui, partial);
    reduce_kernel<<<1, 256, 0, stream>>>(partial, nblocks, 1.0f / (float)B, (float*)d_out);
}

// Round 11
// 141.476 us; speedup vs baseline: 1.0620x; 1.0149x over previous
//
#include <hip/hip_runtime.h>
#include <math.h>

#define NOISE 1e-12f
#define WSZ 1064    // floats per staging buffer: T(264) | G1r(200) | G1i(200) | G2r(200) | G2i(200)
#define WSZ4 266    // = WSZ/4 float4s (all section offsets are float4-aligned)

__device__ __forceinline__ float2 cmul(float2 a, float2 b) {
    return make_float2(a.x*b.x - a.y*b.y, a.x*b.y + a.y*b.x);
}
// conj(a)*b
__device__ __forceinline__ float2 cconjmul(float2 a, float2 b) {
    return make_float2(a.x*b.x + a.y*b.y, a.x*b.y - a.y*b.x);
}
// a*conj(b)
__device__ __forceinline__ float2 cmulconj(float2 a, float2 b) {
    return make_float2(a.x*b.x + a.y*b.y, a.y*b.x - a.x*b.y);
}
__device__ __forceinline__ float2 cadd(float2 a, float2 b){ return make_float2(a.x+b.x, a.y+b.y); }
__device__ __forceinline__ float2 csub(float2 a, float2 b){ return make_float2(a.x-b.x, a.y-b.y); }
__device__ __forceinline__ float2 cscale(float s, float2 a){ return make_float2(s*a.x, s*a.y); }

// async global->LDS, 16 B per lane (fire-and-forget; counted by vmcnt)
typedef const void __attribute__((address_space(1)))* gas_t;
typedef void __attribute__((address_space(3)))* las_t;
__device__ __forceinline__ void gll16(const float* g, float* l) {
    __builtin_amdgcn_global_load_lds((gas_t)g, (las_t)l, 16, 0, 0);
}

// one wave per batch element iteration; 4 waves/block; 4 iterations -> 16 b per block
__global__ __launch_bounds__(256) void rate_kernel(
    const float* __restrict__ t1,
    const float* __restrict__ G1r, const float* __restrict__ G1i,
    const float* __restrict__ G2r, const float* __restrict__ G2i,
    const float* __restrict__ Ur,  const float* __restrict__ Ui,
    float* __restrict__ partial)
{
    __shared__ float4 lds4[4 * 2 * WSZ4];  // per-wave double-buffered staging (16B-aligned)
    __shared__ float2 ent[4][4][16];       // [wave][it][entry]
    __shared__ float wsum[4];
    const int wave = threadIdx.x >> 6;
    const int lane = threadIdx.x & 63;
    const int t  = lane & 7;     // output column of phi
    const int k0 = lane >> 3;    // k-block id: lane handles k = 4*k0 + c + 32*j, c=0..3
    const int e8 = k0;
    const int nn = (e8 >> 1) & 1;   // = lane bit 4
    const int rr = e8 & 1;
    float* Wbuf = (float*)(lds4 + wave * 2 * WSZ4);

    // stage b's theta/G/F row into LDS buffer `dst` (6 vmcnt-counted issues)
    #define STAGE(dst, bb) {                                                  \
        const float* tb_ = t1 + (long)(bb) * 264;                             \
        gll16(tb_ + lane * 4, (dst));                 /* T[0..255]   */       \
        if (lane < 2)  gll16(tb_ + 256 + lane * 4, (dst) + 256);              \
        if (lane < 50) {                                                      \
            gll16(G1r + (long)(bb) * 200 + lane * 4, (dst) + 264);            \
            gll16(G1i + (long)(bb) * 200 + lane * 4, (dst) + 464);            \
            gll16(G2r + (long)(bb) * 200 + lane * 4, (dst) + 664);            \
            gll16(G2i + (long)(bb) * 200 + lane * 4, (dst) + 864);            \
        }                                                                     \
    }

    const long bbase = (long)blockIdx.x * 16 + (long)wave * 4;
    STAGE(Wbuf, bbase);   // prologue: buffer 0 for it 0

    const float* urb = Ur + bbase * 800;
    const float* uib = Ui + bbase * 800;
    const int uoff = 32 * k0 + t;   // U flat base for (k0,t); per (j,c): + 256j + 8c
    #define LDU2(idx) make_float2(urb[(idx)], uib[(idx)])

    // initial U prefetch for it 0, j=0 (c=0..3)
    float2 u0 = LDU2(uoff), u1 = LDU2(uoff+8), u2 = LDU2(uoff+16), u3 = LDU2(uoff+24);

    // per-k math: w = theta*u, then p += G*w for 4 G rows
    #define CMATH(thr,thi, ar,ai, cr,ci, dr,di, er,ei, u) {      \
        float wr = (thr)*(u).x - (thi)*(u).y;                    \
        float wi = (thr)*(u).y + (thi)*(u).x;                    \
        p[0] += (ar)*wr - (ai)*wi;  p[1] += (ar)*wi + (ai)*wr;   \
        p[2] += (cr)*wr - (ci)*wi;  p[3] += (cr)*wi + (ci)*wr;   \
        p[4] += (dr)*wr - (di)*wi;  p[5] += (dr)*wi + (di)*wr;   \
        p[6] += (er)*wr - (ei)*wi;  p[7] += (er)*wi + (ei)*wr; }

    // one j-group: 10 ds_read_b128 (1 vaddr + imm offsets) + 4 CMATH
    #define JGROUP(q, U0, U1, U2, U3) {                                   \
        float4 tr  = F4[(q)];        float4 ti  = F4[25  + (q)];          \
        float4 a0r = F4[66  + (q)];  float4 a0i = F4[116 + (q)];          \
        float4 a1r = F4[91  + (q)];  float4 a1i = F4[141 + (q)];          \
        float4 b0r = F4[166 + (q)];  float4 b0i = F4[216 + (q)];          \
        float4 b1r = F4[191 + (q)];  float4 b1i = F4[241 + (q)];          \
        CMATH(tr.x,ti.x, a0r.x,a0i.x, a1r.x,a1i.x, b0r.x,b0i.x, b1r.x,b1i.x, U0); \
        CMATH(tr.y,ti.y, a0r.y,a0i.y, a1r.y,a1i.y, b0r.y,b0i.y, b1r.y,b1i.y, U1); \
        CMATH(tr.z,ti.z, a0r.z,a0i.z, a1r.z,a1i.z, b0r.z,b0i.z, b1r.z,b1i.z, U2); \
        CMATH(tr.w,ti.w, a0r.w,a0i.w, a1r.w,a1i.w, b0r.w,b0i.w, b1r.w,b1i.w, U3); }

    for (int it = 0; it < 4; ++it) {
        float* W = Wbuf + (it & 1) * WSZ;
        const float4* F4 = (const float4*)W;

        // issue next it's staging first (flies under this it's compute).
        // Outstanding at the wait: [8 prefetched U][6 new gll] = 14 ->
        // vmcnt(14) drains exactly the CURRENT buffer's staging.
        if (it < 3) {
            STAGE(Wbuf + ((it + 1) & 1) * WSZ, bbase + it + 1);
            asm volatile("s_waitcnt vmcnt(14)" ::: "memory");
        }
        __builtin_amdgcn_sched_barrier(0);

        // phi partials: [0,1]=phi1 n0 re/im, [2,3]=phi1 n1, [4,5]=phi2 n0, [6,7]=phi2 n1
        float p[8] = {0,0,0,0,0,0,0,0};

        #pragma unroll 1   // rolled: keep VGPR bounded; prefetch provides ILP
        for (int j = 0; j < 3; ++j) {
            float2 n0, n1, n2, n3;
            if (j < 2) {
                const int nb = uoff + 256 * (j + 1);
                n0 = LDU2(nb); n1 = LDU2(nb+8); n2 = LDU2(nb+16); n3 = LDU2(nb+24);
            } else {
                // tail strips k=96..99: idx <= 792+7 = 799, in-bounds for all lanes
                n0 = LDU2(768+t); n1 = LDU2(776+t); n2 = LDU2(784+t); n3 = LDU2(792+t);
            }
            JGROUP(k0 + 8*j, u0, u1, u2, u3);
            u0 = n0; u1 = n1; u2 = n2; u3 = n3;
        }
        // tail: k = 96+c, only k0==0 lanes contribute (q = 96/4 = 24)
        if (k0 == 0) {
            JGROUP(24, u0, u1, u2, u3);
        }

        // cross-it U prefetch: issue next it's j=0 strips NOW; the shuffle
        // phase below covers their latency.
        if (it < 3) {
            urb += 800; uib += 800;
            u0 = LDU2(uoff); u1 = LDU2(uoff+8); u2 = LDU2(uoff+16); u3 = LDU2(uoff+24);
        }

        // reduce over the 8 k-blocks (lane bits 3..5): stages 8 and 32 on all 8
        // partials, then exchange-then-add on bit 4 (keep nn, send 1-nn).
        #pragma unroll
        for (int q = 0; q < 8; ++q) {
            p[q] += __shfl_xor(p[q], 8);
            p[q] += __shfl_xor(p[q], 32);
        }
        float4 ph;
        {
            float k0r = nn ? p[2] : p[0], s0r = nn ? p[0] : p[2];
            float k0i = nn ? p[3] : p[1], s0i = nn ? p[1] : p[3];
            float k1r = nn ? p[6] : p[4], s1r = nn ? p[4] : p[6];
            float k1i = nn ? p[7] : p[5], s1i = nn ? p[5] : p[7];
            ph.x = k0r + __shfl_xor(s0r, 16);
            ph.y = k0i + __shfl_xor(s0i, 16);
            ph.z = k1r + __shfl_xor(s1r, 16);
            ph.w = k1i + __shfl_xor(s1i, 16);
        }

        // ---- F norms: scale_h = sqrt(2 / sum|F_h|^2) ----  (F from LDS T region)
        float s1, s2;
        {
            int idx = lane & 15;
            int sel = (lane >> 4) & 1;
            float fr = W[200 + sel*32 + idx];
            float fi = W[216 + sel*32 + idx];
            float m = fr*fr + fi*fi;
            #pragma unroll
            for (int s = 1; s < 16; s <<= 1) m += __shfl_xor(m, s);
            float other = __shfl_xor(m, 16);
            float nrm1 = sel ? other : m;
            float nrm2 = sel ? m : other;
            s1 = sqrtf(2.0f / nrm1);
            s2 = sqrtf(2.0f / nrm2);
        }

        // ---- A/C entries: ent[it][0..7] = {A,C} for R1; [8..15] for R2 ----
        {
            int jf = t*2 + rr;
            float2 f1 = make_float2(W[200 + jf], W[216 + jf]);
            float2 f2 = make_float2(W[232 + jf], W[248 + jf]);
            float2 phi1n = make_float2(ph.x, ph.y);
            float2 phi2n = make_float2(ph.z, ph.w);
            bool lo = (e8 < 4);
            float2 E0 = cmul(phi1n, lo ? f1 : f2);
            float2 E1 = cmul(phi2n, lo ? f2 : f1);
            #pragma unroll
            for (int s = 1; s < 8; s <<= 1) {
                E0.x += __shfl_xor(E0.x, s); E0.y += __shfl_xor(E0.y, s);
                E1.x += __shfl_xor(E1.x, s); E1.y += __shfl_xor(E1.y, s);
            }
            if (t == 0) {
                ent[wave][it][e8]     = cscale(lo ? s1 : s2, E0);
                ent[wave][it][e8 + 8] = cscale(lo ? s2 : s1, E1);
            }
        }
    }
    #undef STAGE
    #undef LDU2
    #undef CMATH
    #undef JGROUP
    asm volatile("s_waitcnt lgkmcnt(0)" ::: "memory");
    __builtin_amdgcn_wave_barrier();

    // ---- batched 2x2 complex rate: lanes 0..7 -> (it = lane>>1, R1/R2 = lane&1) ----
    float negR = 0.0f;
    if (lane < 8) {
        const float2* e = &ent[wave][lane >> 1][(lane & 1) * 8];
        float2 A00=e[0], A01=e[1], A10=e[2], A11=e[3];
        float2 C00=e[4], C01=e[5], C10=e[6], C11=e[7];
        float mu00 = C00.x*C00.x + C00.y*C00.y + C01.x*C01.x + C01.y*C01.y + NOISE;
        float mu11 = C10.x*C10.x + C10.y*C10.y + C11.x*C11.x + C11.y*C11.y + NOISE;
        float2 mu01 = cadd(cmulconj(C00, C10), cmulconj(C01, C11));
        mu01.x += NOISE;
        float det = mu00*mu11 - (mu01.x*mu01.x + mu01.y*mu01.y);
        float inv = 1.0f / det;
        float2 mu01c = make_float2(mu01.x, -mu01.y);
        float2 X00 = cscale(inv, csub(cscale(mu11, A00), cmul(mu01,  A10)));
        float2 X01 = cscale(inv, csub(cscale(mu11, A01), cmul(mu01,  A11)));
        float2 X10 = cscale(inv, csub(cscale(mu00, A10), cmul(mu01c, A00)));
        float2 X11 = cscale(inv, csub(cscale(mu00, A11), cmul(mu01c, A01)));
        float2 I00 = cadd(cconjmul(A00, X00), cconjmul(A10, X10));
        float2 I01 = cadd(cconjmul(A00, X01), cconjmul(A10, X11));
        float2 I10 = cadd(cconjmul(A01, X00), cconjmul(A11, X10));
        float2 I11 = cadd(cconjmul(A01, X01), cconjmul(A11, X11));
        I00.x += 1.0f; I01.x += 1.0f; I10.x += 1.0f; I11.x += 1.0f;
        float2 dT = csub(cmul(I00, I11), cmul(I01, I10));
        negR = -0.5f * logf(dT.x*dT.x + dT.y*dT.y);  // -Re(log z) = -ln|z|
    }
    // pairwise max over (R1,R2), then sum the 4 batch elements
    float m = fmaxf(negR, __shfl_xor(negR, 1));
    m += __shfl_xor(m, 2);
    m += __shfl_xor(m, 4);
    if (lane == 0) wsum[wave] = m;

    __syncthreads();
    if (threadIdx.x == 0)
        partial[blockIdx.x] = (wsum[0] + wsum[1]) + (wsum[2] + wsum[3]);
}

__global__ __launch_bounds__(256) void reduce_kernel(
    const float* __restrict__ partial, int n, float invB, float* __restrict__ out)
{
    __shared__ float sd[256];
    float s = 0.0f;
    for (int i = threadIdx.x; i < n; i += 256) s += partial[i];
    sd[threadIdx.x] = s;
    __syncthreads();
    for (int o = 128; o > 0; o >>= 1) {
        if ((int)threadIdx.x < o) sd[threadIdx.x] += sd[threadIdx.x + o];
        __syncthreads();
    }
    if (threadIdx.x == 0) out[0] = sd[0] * invB;
}

extern "C" void kernel_launch(void* const* d_in, const int* in_sizes, int n_in,
                              void* d_out, int out_size, void* d_ws, size_t ws_size,
                              hipStream_t stream) {
    const float* t1  = (const float*)d_in[0];
    const float* G1r = (const float*)d_in[1];
    const float* G1i = (const float*)d_in[2];
    const float* G2r = (const float*)d_in[3];
    const float* G2i = (const float*)d_in[4];
    const float* Ur  = (const float*)d_in[5];
    const float* Ui  = (const float*)d_in[6];

    const int B = in_sizes[0] / 264;        // 65536
    const int nblocks = B / 16;             // 16 batch elements per block
    float* partial = (float*)d_ws;          // nblocks floats

    rate_kernel<<<nblocks, 256, 0, stream>>>(t1, G1r, G1i, G2r, G2i, Ur, Ui, partial);
    reduce_kernel<<<1, 256, 0, stream>>>(partial, nblocks, 1.0f / (float)B, (float*)d_out);
}